// Round 2
// baseline (289.310 us; speedup 1.0000x reference)
//
#include <hip/hip_runtime.h>
#include <math.h>

#define NN 50000
#define EE 800000
#define RR 2
#define LL 2
#define DD 128
#define GG 64
#define CCLS 8
#define NBUK 196     // buckets of 256 dst nodes: bucket = dst >> 8
#define BCAP 6144    // max raw edges per bucket (mean 4082, sigma 64)
#define BCI  7424    // per-bucket CSR capacity: BCAP + 256 self + 3*256 pad4 + 16 tail

typedef unsigned int uint;
typedef unsigned short ushort;
typedef short bf16x8 __attribute__((ext_vector_type(8)));
typedef float f32x4 __attribute__((ext_vector_type(4)));
typedef float f32x2 __attribute__((ext_vector_type(2)));

// ---------------- workspace layout (bytes) ----------------
#define OFF_H1    ((size_t)0)            // [N][64] uint packed bf16      12,800,000
#define OFF_WBT   ((size_t)12800000)     // [L][R][128][128] bf16            131,072
#define OFF_ISD   ((size_t)12931072)     // [2][N] f32                       400,000
#define OFF_RP    ((size_t)13331072)     // rps[2][N] + rpc[2][N] i32        800,000
#define OFF_CI    ((size_t)14131072)     // [2][196][BCI] i32             11,640,832
#define OFF_ZERO  ((size_t)25771904)     // 34,624
#define OFF_BD    ((size_t)25806592)     // [2][196][BCAP] uint            9,633,792
#define OFF_XW    ((size_t)25806592)     // ALIAS of BD (bdata dead after k_csr):
                                         // [2][N+1][128] fp8             12,800,256
// zero region internal offsets (bytes)
#define ZO_GCUR 0        // [2][196] i32 bucket counters (1568 B, pad 1600)
#define ZO_SUM  1600     // [G][D] f32 (32768 B)
#define ZO_CNT  34368    // [G] i32 (256 B)
#define ZERO_BYTES 34624

static __device__ __forceinline__ ushort f2b(float f) {
  uint u = __float_as_uint(f);
  uint r = (u + 0x7fffu + ((u >> 16) & 1u)) >> 16;
  return (ushort)r;
}
static __device__ __forceinline__ float blo(uint u) { return __uint_as_float(u << 16); }
static __device__ __forceinline__ float bhi(uint u) { return __uint_as_float(u & 0xffff0000u); }

// ---------------- W prep: fp32 W[l][r][k][n] -> bf16 WbfT[l][r][n][k] ----------------
__global__ __launch_bounds__(256) void k_wprep(const float* __restrict__ W,
                                               ushort* __restrict__ WT) {
  int idx = blockIdx.x * 256 + threadIdx.x;  // 65536 total
  int lr = idx >> 14;
  int rem = idx & 16383;
  int n = rem >> 7, k = rem & 127;
  WT[lr * 16384 + n * 128 + k] = f2b(W[lr * 16384 + k * 128 + n]);
}

// ---------------- phase 1: partition edges into dst buckets (coalesced) ----------------
__global__ __launch_bounds__(256) void k_part(const int* __restrict__ EI,
                                              int* __restrict__ gcur,
                                              uint* __restrict__ bdata) {
  __shared__ int hist[256];   // bucket counts -> stage-exclusive offsets
  __shared__ int sbase[256];  // scan scratch
  __shared__ int gbase[256];  // global reservation base per bucket
  __shared__ int lcur[256];
  __shared__ uint stage[4096];
  __shared__ unsigned char bstage[4096];
  const int r = blockIdx.y;
  const int t = threadIdx.x;
  const int e0 = blockIdx.x * 4096;
  const int cnt = min(4096, EE - e0);
  hist[t] = 0;
  lcur[t] = 0;
  __syncthreads();

  int src[16], dst[16];
  bool val[4];
#pragma unroll
  for (int j = 0; j < 4; ++j) {
    int i4 = (j * 256 + t) * 4;
    val[j] = (i4 < cnt);
    if (val[j]) {
      int4 s4 = *(const int4*)(EI + (size_t)r * 2 * EE + e0 + i4);
      int4 d4 = *(const int4*)(EI + (size_t)r * 2 * EE + EE + e0 + i4);
      src[j * 4 + 0] = s4.x; src[j * 4 + 1] = s4.y; src[j * 4 + 2] = s4.z; src[j * 4 + 3] = s4.w;
      dst[j * 4 + 0] = d4.x; dst[j * 4 + 1] = d4.y; dst[j * 4 + 2] = d4.z; dst[j * 4 + 3] = d4.w;
#pragma unroll
      for (int i = 0; i < 4; ++i) atomicAdd(&hist[dst[j * 4 + i] >> 8], 1);
    }
  }
  __syncthreads();
  int hv = hist[t];
  if (t < NBUK && hv > 0)
    gbase[t] = atomicAdd(&gcur[r * NBUK + t], hv);
  else
    gbase[t] = 0;
  sbase[t] = hv;
  __syncthreads();
  for (int off = 1; off < 256; off <<= 1) {
    int u = (t >= off) ? sbase[t - off] : 0;
    __syncthreads();
    sbase[t] += u;
    __syncthreads();
  }
  int incl = sbase[t];
  hist[t] = incl - hv;  // exclusive stage offset
  __syncthreads();
#pragma unroll
  for (int j = 0; j < 4; ++j) {
    if (val[j]) {
#pragma unroll
      for (int i = 0; i < 4; ++i) {
        int d = dst[j * 4 + i];
        int b = d >> 8;
        int p = atomicAdd(&lcur[b], 1);
        int pos = hist[b] + p;
        stage[pos] = ((uint)src[j * 4 + i] << 8) | (uint)(d & 255);
        bstage[pos] = (unsigned char)b;
      }
    }
  }
  __syncthreads();
  for (int s = t; s < cnt; s += 256) {
    int b = (int)bstage[s];
    bdata[(size_t)(r * NBUK + b) * BCAP + gbase[b] + (s - hist[b])] = stage[s];
  }
}

// ---------------- phase 2: per-bucket padded CSR with explicit self edges ----------------
// Each node's segment = [in-edges..., self, NN-pads] padded to a multiple of 4.
// Row NN of the fp8 table is all-zero, so pad slots add 0 with no branch in k_agg.
__global__ __launch_bounds__(256) void k_csr(const uint* __restrict__ bdata,
                                             const int* __restrict__ gcur,
                                             float* __restrict__ isd,
                                             int* __restrict__ rps,
                                             int* __restrict__ rpc,
                                             int* __restrict__ ci) {
  __shared__ int lcnt[256];
  __shared__ int lrp[256];
  __shared__ int lcur[256];
  __shared__ int cstage[BCI];
  __shared__ int shtot;
  const int b = blockIdx.x;
  const int r = blockIdx.y;
  const int t = threadIdx.x;
  const int cnt = gcur[r * NBUK + b];
  const uint* bd = bdata + (size_t)(r * NBUK + b) * BCAP;
  lcnt[t] = 0;
  lcur[t] = 0;
  __syncthreads();
  for (int s = t; s < cnt; s += 256) atomicAdd(&lcnt[bd[s] & 255u], 1);
  __syncthreads();
  const int deg = lcnt[t];
  const int node = b * 256 + t;
  const int valid = (node < NN) ? 1 : 0;
  const int deg3 = valid ? ((deg + 1 + 3) & ~3) : 0;  // self + pad to %4
  lrp[t] = deg3;
  __syncthreads();
  for (int off = 1; off < 256; off <<= 1) {
    int u = (t >= off) ? lrp[t - off] : 0;
    __syncthreads();
    lrp[t] += u;
    __syncthreads();
  }
  int incl = lrp[t];
  if (t == 255) shtot = incl;
  __syncthreads();
  lrp[t] = incl - deg3;  // exclusive
  __syncthreads();
  const int ex = lrp[t];
  if (valid) {
    isd[r * NN + node] = rsqrtf((float)(deg + 1));
    rps[r * NN + node] = b * BCI + ex;
    rpc[r * NN + node] = deg3;
    cstage[ex + deg] = node;  // self edge at end of real entries
    for (int p = deg + 1; p < deg3; ++p) cstage[ex + p] = NN;  // zero-row pads
  }
  const int btot = shtot;          // <= BCAP + 4*256 = 7168; +16 <= BCI
  if (t < 16) cstage[btot + t] = NN;  // tail pad for k_agg prefetch over-read
  __syncthreads();
  for (int s = t; s < cnt; s += 256) {
    uint pr = bd[s];
    int j = (int)(pr & 255u);
    int p = atomicAdd(&lcur[j], 1);
    cstage[lrp[j] + p] = (int)(pr >> 8);
  }
  __syncthreads();
  const int on = btot + 16;
  int* co = ci + (size_t)r * (NBUK * BCI) + (size_t)b * BCI;
  for (int s = t; s < on; s += 256) co[s] = cstage[s];
}

// ---------------- MFMA GEMM: xw'[r][m][:] = (X[m][:] @ W[r]) * isd[r][m], fp8 out ----------------
#define AL_S 72    // 64+8 bf16 row stride
#define WT_S 136   // 128+8 bf16 row stride
template <int IN_BF16>
__global__ __launch_bounds__(256) void k_gemm(const void* __restrict__ Xv,
                                              const ushort* __restrict__ WTg,
                                              const float* __restrict__ isd,
                                              uint* __restrict__ Y) {
  __shared__ ushort WTl[128 * WT_S];
  __shared__ ushort Al[128 * AL_S];
  const int r = blockIdx.y;
  const int m0b = blockIdx.x * 128;
  const int t = threadIdx.x;
  const int w = t >> 6, L = t & 63, q = L >> 4, ln = L & 15;
  uint* Yr = Y + (size_t)r * (NN + 1) * 32;   // fp8 row = 32 uints, +1 zero row
  const ushort* WTr = WTg + (size_t)r * 16384;

#pragma unroll
  for (int i = 0; i < 8; ++i) {
    int g = t + i * 256;
    int n = g >> 4, k0 = (g & 15) * 8;
    *(uint4*)(&WTl[n * WT_S + k0]) = *(const uint4*)(WTr + n * 128 + k0);
  }

  f32x4 acc[2][8];
#pragma unroll
  for (int mt = 0; mt < 2; ++mt)
#pragma unroll
    for (int nt = 0; nt < 8; ++nt) {
      acc[mt][nt][0] = 0.f; acc[mt][nt][1] = 0.f;
      acc[mt][nt][2] = 0.f; acc[mt][nt][3] = 0.f;
    }

  for (int hh = 0; hh < 2; ++hh) {
    __syncthreads();
    {
      int row = t >> 1, ch = t & 1;
      int gm = m0b + row;
      ushort* dst = &Al[row * AL_S + ch * 32];
      if (gm < NN) {
        if (IN_BF16) {
          const uint4* xp = (const uint4*)((const ushort*)Xv + (size_t)gm * 128 + hh * 64 + ch * 32);
#pragma unroll
          for (int j = 0; j < 4; ++j) ((uint4*)dst)[j] = xp[j];
        } else {
          const float4* xp = (const float4*)((const float*)Xv + (size_t)gm * 128 + hh * 64 + ch * 32);
          ushort tmp[32];
#pragma unroll
          for (int j = 0; j < 8; ++j) {
            float4 v = xp[j];
            tmp[j * 4 + 0] = f2b(v.x); tmp[j * 4 + 1] = f2b(v.y);
            tmp[j * 4 + 2] = f2b(v.z); tmp[j * 4 + 3] = f2b(v.w);
          }
#pragma unroll
          for (int j = 0; j < 4; ++j) ((uint4*)dst)[j] = ((uint4*)tmp)[j];
        }
      } else {
        uint4 z = make_uint4(0, 0, 0, 0);
#pragma unroll
        for (int j = 0; j < 4; ++j) ((uint4*)dst)[j] = z;
      }
    }
    __syncthreads();
#pragma unroll
    for (int kk = 0; kk < 2; ++kk) {
      bf16x8 b0 = *(const bf16x8*)(&Al[(w * 32 + ln) * AL_S + kk * 32 + q * 8]);
      bf16x8 b1 = *(const bf16x8*)(&Al[(w * 32 + 16 + ln) * AL_S + kk * 32 + q * 8]);
#pragma unroll
      for (int nt = 0; nt < 8; ++nt) {
        bf16x8 a = *(const bf16x8*)(&WTl[(nt * 16 + ln) * WT_S + hh * 64 + kk * 32 + q * 8]);
        acc[0][nt] = __builtin_amdgcn_mfma_f32_16x16x32_bf16(a, b0, acc[0][nt], 0, 0, 0);
        acc[1][nt] = __builtin_amdgcn_mfma_f32_16x16x32_bf16(a, b1, acc[1][nt], 0, 0, 0);
      }
    }
  }
  // epilogue: lane holds D for m = m0b + w*32 + mt*16 + ln, n = nt*16 + q*4 + reg
  // m == NN is the zero row used by k_agg's pad slots (acc==0 there since Al was zeroed).
#pragma unroll
  for (int mt = 0; mt < 2; ++mt) {
    int m = m0b + w * 32 + mt * 16 + ln;
    if (m <= NN) {
      float sc = (m < NN) ? isd[r * NN + m] : 0.f;
      uint* yp = Yr + (size_t)m * 32;
#pragma unroll
      for (int nt = 0; nt < 8; ++nt) {
        f32x4 v = acc[mt][nt];
        uint u = __builtin_amdgcn_cvt_pk_fp8_f32(v[0] * sc, v[1] * sc, 0u, false);
        u = __builtin_amdgcn_cvt_pk_fp8_f32(v[2] * sc, v[3] * sc, u, true);
        yp[nt * 4 + q] = u;
      }
    }
  }
}

// ---------------- aggregation: 1 wave/node, 4 edges in flight, uint2 gathers ----------------
// lane = g*16 + c: g = edge slot (0..3), c = channel-octet (8 fp8 channels = 1 uint2).
// CSR segments are padded (self edge + zero-row pads to %4), so the inner loop has
// NO bounds checks: every slot converts and accumulates (pads add 0.0).
// f32x2 accumulators -> v_pk_add_f32 / v_pk_fma_f32; gather is double-buffered.
__global__ __launch_bounds__(256) void k_agg(const char* __restrict__ xw,
                                             const int* __restrict__ rps,
                                             const int* __restrict__ rpc,
                                             const int* __restrict__ ci,
                                             const float* __restrict__ isd,
                                             const float* __restrict__ bias,
                                             uint* __restrict__ hout, int relu_flag) {
  const int w = threadIdx.x >> 6;
  const int lane = threadIdx.x & 63;
  const int g = lane >> 4, c = lane & 15;
  const int i = blockIdx.x * 4 + w;
  const uint cb = (uint)c * 8u;

  f32x2 tot[4];
#pragma unroll
  for (int j = 0; j < 4; ++j) { tot[j][0] = 0.f; tot[j][1] = 0.f; }

#pragma unroll
  for (int r = 0; r < RR; ++r) {
    const char* xwr = xw + (size_t)r * ((size_t)(NN + 1) * 128);
    const int e0 = rps[r * NN + i];
    const int total = rpc[r * NN + i];          // multiple of 4, >= 4
    const int* ce = ci + (size_t)r * (NBUK * BCI) + e0;
    const float di = isd[r * NN + i];

    f32x2 acc[4];
#pragma unroll
    for (int j = 0; j < 4; ++j) { acc[j][0] = 0.f; acc[j][1] = 0.f; }

    int s0 = ce[g];
    uint2 ucur = *(const uint2*)(xwr + (((uint)s0 << 7) + cb));
    int s1 = ce[4 + g];
    int ip = 8 + g;
    for (int base = 0; base < total; base += 4) {
      uint2 unext = *(const uint2*)(xwr + (((uint)s1 << 7) + cb));  // prefetch next group
      int s2 = ce[ip];
      ip += 4;
      f32x2 v;
      v = __builtin_amdgcn_cvt_pk_f32_fp8(ucur.x, false); acc[0] += v;
      v = __builtin_amdgcn_cvt_pk_f32_fp8(ucur.x, true);  acc[1] += v;
      v = __builtin_amdgcn_cvt_pk_f32_fp8(ucur.y, false); acc[2] += v;
      v = __builtin_amdgcn_cvt_pk_f32_fp8(ucur.y, true);  acc[3] += v;
      ucur = unext;
      s1 = s2;
    }
    f32x2 d2; d2[0] = di; d2[1] = di;
#pragma unroll
    for (int j = 0; j < 4; ++j) tot[j] += acc[j] * d2;
  }

  // reduce over the 4 edge slots (lane bits 4,5)
#pragma unroll
  for (int mask = 16; mask <= 32; mask <<= 1) {
#pragma unroll
    for (int j = 0; j < 4; ++j) {
      f32x2 o;
      o[0] = __shfl_xor(tot[j][0], mask);
      o[1] = __shfl_xor(tot[j][1], mask);
      tot[j] += o;
    }
  }

  // lanes g==0 write channels [c*8, c*8+8) as 4 packed bf16 uints
  if (g == 0) {
    const int ch0 = c * 8;
    const float4* b0p = (const float4*)(bias + ch0);
    const float4* b1p = (const float4*)(bias + DD + ch0);
    float4 ba = b0p[0], bb = b0p[1], bc = b1p[0], bd = b1p[1];
    float o[8] = {tot[0][0], tot[0][1], tot[1][0], tot[1][1],
                  tot[2][0], tot[2][1], tot[3][0], tot[3][1]};
    o[0] += ba.x + bc.x; o[1] += ba.y + bc.y; o[2] += ba.z + bc.z; o[3] += ba.w + bc.w;
    o[4] += bb.x + bd.x; o[5] += bb.y + bd.y; o[6] += bb.z + bd.z; o[7] += bb.w + bd.w;
    if (relu_flag) {
#pragma unroll
      for (int j = 0; j < 8; ++j) o[j] = fmaxf(o[j], 0.f);
    }
    uint4 pk;
    pk.x = (uint)f2b(o[0]) | ((uint)f2b(o[1]) << 16);
    pk.y = (uint)f2b(o[2]) | ((uint)f2b(o[3]) << 16);
    pk.z = (uint)f2b(o[4]) | ((uint)f2b(o[5]) << 16);
    pk.w = (uint)f2b(o[6]) | ((uint)f2b(o[7]) << 16);
    ((uint4*)(hout + (size_t)i * 64))[c] = pk;
  }
}

// ---------------- pooling (batch ids sorted), packed bf16 input ----------------
#define PCHUNK 32
__global__ __launch_bounds__(64) void k_pool(const uint* __restrict__ h,
                                             const int* __restrict__ batch,
                                             float* __restrict__ sums,
                                             int* __restrict__ counts) {
  int lane = threadIdx.x;
  int n0 = blockIdx.x * PCHUNK;
  int n1 = n0 + PCHUNK;
  if (n1 > NN) n1 = NN;
  if (n0 >= NN) return;
  float aLo = 0.f, aHi = 0.f;
  int cnt = 0;
  int g = batch[n0];
  uint u = h[(size_t)n0 * 64 + lane];
  for (int n = n0; n < n1; ++n) {
    uint unext = 0;
    int gnext = g;
    if (n + 1 < n1) {
      unext = h[(size_t)(n + 1) * 64 + lane];
      gnext = batch[n + 1];
    }
    aLo += blo(u);
    aHi += bhi(u);
    cnt++;
    if (n + 1 < n1 && gnext != g) {
      atomicAdd(&sums[g * DD + lane * 2], aLo);
      atomicAdd(&sums[g * DD + lane * 2 + 1], aHi);
      if (lane == 0) atomicAdd(&counts[g], cnt);
      aLo = 0.f; aHi = 0.f; cnt = 0;
      g = gnext;
    }
    u = unext;
  }
  atomicAdd(&sums[g * DD + lane * 2], aLo);
  atomicAdd(&sums[g * DD + lane * 2 + 1], aHi);
  if (lane == 0) atomicAdd(&counts[g], cnt);
}

__global__ __launch_bounds__(512) void k_final(const float* __restrict__ sums,
                                               const int* __restrict__ counts,
                                               const float* __restrict__ lin_w,
                                               const float* __restrict__ lin_b,
                                               float* __restrict__ out) {
  int t = threadIdx.x;  // 512 = 64 graphs x 8 classes
  int g = t >> 3, co = t & 7;
  float cnt = (float)counts[g];
  if (cnt < 1.f) cnt = 1.f;
  float inv = 1.f / cnt;
  float v = lin_b[co];
  for (int d = 0; d < DD; ++d) v += (sums[g * DD + d] * inv) * lin_w[d * CCLS + co];
  out[t] = v;
}

extern "C" void kernel_launch(void* const* d_in, const int* in_sizes, int n_in,
                              void* d_out, int out_size, void* d_ws, size_t ws_size,
                              hipStream_t stream) {
  (void)in_sizes; (void)n_in; (void)out_size; (void)ws_size;
  const float* x     = (const float*)d_in[0];
  const float* W     = (const float*)d_in[1];
  const float* b     = (const float*)d_in[2];
  const float* lin_w = (const float*)d_in[3];
  const float* lin_b = (const float*)d_in[4];
  const int*   EI    = (const int*)d_in[5];
  const int*   batch = (const int*)d_in[6];
  float* out = (float*)d_out;

  char* ws = (char*)d_ws;
  uint*   h1    = (uint*)(ws + OFF_H1);       // bf16 packed
  ushort* WbfT  = (ushort*)(ws + OFF_WBT);
  float*  isd   = (float*)(ws + OFF_ISD);
  int*    rps   = (int*)(ws + OFF_RP);
  int*    rpc   = rps + 2 * NN;
  int*    ci    = (int*)(ws + OFF_CI);
  uint*   bdata = (uint*)(ws + OFF_BD);
  uint*   xw    = (uint*)(ws + OFF_XW);       // fp8 table (isd-prescaled), aliases bdata
  char*   zb    = ws + OFF_ZERO;
  int*    gcur  = (int*)(zb + ZO_GCUR);
  float*  sums  = (float*)(zb + ZO_SUM);
  int*    counts= (int*)(zb + ZO_CNT);

  (void)hipMemsetAsync(zb, 0, ZERO_BYTES, stream);

  k_wprep<<<256, 256, 0, stream>>>(W, WbfT);
  k_part<<<dim3((EE + 4095) / 4096, RR), 256, 0, stream>>>(EI, gcur, bdata);
  k_csr<<<dim3(NBUK, RR), 256, 0, stream>>>(bdata, gcur, isd, rps, rpc, ci);

  for (int l = 0; l < LL; ++l) {
    const ushort* WTl_g = WbfT + (size_t)l * RR * DD * DD;
    if (l == 0)
      k_gemm<0><<<dim3((NN + 127) / 128, RR), 256, 0, stream>>>((const void*)x, WTl_g, isd, xw);
    else
      k_gemm<1><<<dim3((NN + 127) / 128, RR), 256, 0, stream>>>((const void*)h1, WTl_g, isd, xw);
    k_agg<<<(NN + 3) / 4, 256, 0, stream>>>((const char*)xw, rps, rpc, ci, isd,
                                            b + (size_t)l * RR * DD, h1,
                                            (l < LL - 1) ? 1 : 0);
  }
  k_pool<<<(NN + PCHUNK - 1) / PCHUNK, 64, 0, stream>>>(h1, batch, sums, counts);
  k_final<<<1, GG * CCLS, 0, stream>>>(sums, counts, lin_w, lin_b, out);
}

// Round 3
// 288.070 us; speedup vs baseline: 1.0043x; 1.0043x over previous
//
#include <hip/hip_runtime.h>
#include <math.h>

#define NN 50000
#define EE 800000
#define RR 2
#define LL 2
#define DD 128
#define GG 64
#define CCLS 8
#define NBUK 196     // buckets of 256 dst nodes: bucket = dst >> 8
#define BCAP 6144    // max raw edges per bucket per relation (mean 4082, sigma 64)
#define BCI2 14080   // merged bucket CSR capacity (r0+r1, each node padded to %8, +32 tail)
                     // realistic worst: 2*(4082+4sig) + 256*2*7 pad + 32 ~= 12.4k < 14080

typedef unsigned int uint;
typedef unsigned short ushort;
typedef short bf16x8 __attribute__((ext_vector_type(8)));
typedef float f32x4 __attribute__((ext_vector_type(4)));
typedef float f32x2 __attribute__((ext_vector_type(2)));

// ---------------- workspace layout (bytes) ----------------
#define OFF_H1    ((size_t)0)            // [N][64] uint packed bf16      12,800,000
#define OFF_WBT   ((size_t)12800000)     // [L][R][128][128] bf16            131,072
#define OFF_ISD   ((size_t)12931072)     // [2][N] f32                       400,000
#define OFF_RP    ((size_t)13331072)     // rps[50176] + rpc[50176] i32      401,408
#define OFF_CI    ((size_t)13732480)     // [196][BCI2] i32               11,038,720
#define OFF_ZERO  ((size_t)24771200)     // 34,624
#define OFF_BD    ((size_t)24805824)     // [2][196][BCAP] uint            9,633,792
#define OFF_XW    ((size_t)24805824)     // ALIAS of BD (bdata dead after k_csr):
                                         // [2][N+1][128] fp8             12,800,256
// zero region internal offsets (bytes)
#define ZO_GCUR 0        // [2][196] i32 bucket counters (1568 B, pad 1600)
#define ZO_SUM  1600     // [G][D] f32 (32768 B)
#define ZO_CNT  34368    // [G] i32 (256 B)
#define ZERO_BYTES 34624

static __device__ __forceinline__ ushort f2b(float f) {
  uint u = __float_as_uint(f);
  uint r = (u + 0x7fffu + ((u >> 16) & 1u)) >> 16;
  return (ushort)r;
}
static __device__ __forceinline__ float blo(uint u) { return __uint_as_float(u << 16); }
static __device__ __forceinline__ float bhi(uint u) { return __uint_as_float(u & 0xffff0000u); }

// ---------------- W prep: fp32 W[l][r][k][n] -> bf16 WbfT[l][r][n][k] ----------------
__global__ __launch_bounds__(256) void k_wprep(const float* __restrict__ W,
                                               ushort* __restrict__ WT) {
  int idx = blockIdx.x * 256 + threadIdx.x;  // 65536 total
  int lr = idx >> 14;
  int rem = idx & 16383;
  int n = rem >> 7, k = rem & 127;
  WT[lr * 16384 + n * 128 + k] = f2b(W[lr * 16384 + k * 128 + n]);
}

// ---------------- phase 1: partition edges into dst buckets (coalesced) ----------------
__global__ __launch_bounds__(256) void k_part(const int* __restrict__ EI,
                                              int* __restrict__ gcur,
                                              uint* __restrict__ bdata) {
  __shared__ int hist[256];   // bucket counts -> stage-exclusive offsets
  __shared__ int sbase[256];  // scan scratch
  __shared__ int gbase[256];  // global reservation base per bucket
  __shared__ int lcur[256];
  __shared__ uint stage[4096];
  __shared__ unsigned char bstage[4096];
  const int r = blockIdx.y;
  const int t = threadIdx.x;
  const int e0 = blockIdx.x * 4096;
  const int cnt = min(4096, EE - e0);
  hist[t] = 0;
  lcur[t] = 0;
  __syncthreads();

  int src[16], dst[16];
  bool val[4];
#pragma unroll
  for (int j = 0; j < 4; ++j) {
    int i4 = (j * 256 + t) * 4;
    val[j] = (i4 < cnt);
    if (val[j]) {
      int4 s4 = *(const int4*)(EI + (size_t)r * 2 * EE + e0 + i4);
      int4 d4 = *(const int4*)(EI + (size_t)r * 2 * EE + EE + e0 + i4);
      src[j * 4 + 0] = s4.x; src[j * 4 + 1] = s4.y; src[j * 4 + 2] = s4.z; src[j * 4 + 3] = s4.w;
      dst[j * 4 + 0] = d4.x; dst[j * 4 + 1] = d4.y; dst[j * 4 + 2] = d4.z; dst[j * 4 + 3] = d4.w;
#pragma unroll
      for (int i = 0; i < 4; ++i) atomicAdd(&hist[dst[j * 4 + i] >> 8], 1);
    }
  }
  __syncthreads();
  int hv = hist[t];
  if (t < NBUK && hv > 0)
    gbase[t] = atomicAdd(&gcur[r * NBUK + t], hv);
  else
    gbase[t] = 0;
  sbase[t] = hv;
  __syncthreads();
  for (int off = 1; off < 256; off <<= 1) {
    int u = (t >= off) ? sbase[t - off] : 0;
    __syncthreads();
    sbase[t] += u;
    __syncthreads();
  }
  int incl = sbase[t];
  hist[t] = incl - hv;  // exclusive stage offset
  __syncthreads();
#pragma unroll
  for (int j = 0; j < 4; ++j) {
    if (val[j]) {
#pragma unroll
      for (int i = 0; i < 4; ++i) {
        int d = dst[j * 4 + i];
        int b = d >> 8;
        int p = atomicAdd(&lcur[b], 1);
        int pos = hist[b] + p;
        stage[pos] = ((uint)src[j * 4 + i] << 8) | (uint)(d & 255);
        bstage[pos] = (unsigned char)b;
      }
    }
  }
  __syncthreads();
  for (int s = t; s < cnt; s += 256) {
    int b = (int)bstage[s];
    bdata[(size_t)(r * NBUK + b) * BCAP + gbase[b] + (s - hist[b])] = stage[s];
  }
}

// ---------------- phase 2: MERGED per-bucket padded CSR ----------------
// Per node: [r0 edges..., self(node), pads(NN) to %8][r1 edges+(NN+1)..., self(NN+1+node),
// pads(NN) to %8]. All nodes of a bucket contiguous, so k_agg streams one pipeline
// across nodes AND relations. rpc packs (ng0 | ng1<<16) group counts.
__global__ __launch_bounds__(256) void k_csr(const uint* __restrict__ bdata,
                                             const int* __restrict__ gcur,
                                             float* __restrict__ isd,
                                             int* __restrict__ rps,
                                             int* __restrict__ rpc,
                                             int* __restrict__ ci) {
  __shared__ int lcnt0[256], lcnt1[256], lrp[256], lex[256], lng[256];
  __shared__ int lcurA[256], lcurB[256];
  __shared__ int cstage[BCI2];   // 56,320 B (+7 KB arrays = 63.5 KB, under 64 KB)
  __shared__ int shtot;
  const int b = blockIdx.x;
  const int t = threadIdx.x;
  const int cnt0 = gcur[b];
  const int cnt1 = gcur[NBUK + b];
  const uint* bd0 = bdata + (size_t)b * BCAP;
  const uint* bd1 = bdata + (size_t)(NBUK + b) * BCAP;
  lcnt0[t] = 0; lcnt1[t] = 0; lcurA[t] = 0; lcurB[t] = 0;
  __syncthreads();
  for (int s = t; s < cnt0; s += 256) atomicAdd(&lcnt0[bd0[s] & 255u], 1);
  for (int s = t; s < cnt1; s += 256) atomicAdd(&lcnt1[bd1[s] & 255u], 1);
  __syncthreads();
  const int deg0 = lcnt0[t];
  const int deg1 = lcnt1[t];
  const int node = b * 256 + t;
  const int valid = (node < NN) ? 1 : 0;
  const int ng0 = valid ? ((deg0 + 8) >> 3) : 0;   // ceil((deg0+1)/8)
  const int ng1 = valid ? ((deg1 + 8) >> 3) : 0;
  const int sz = (ng0 + ng1) << 3;
  lrp[t] = sz;
  __syncthreads();
  for (int off = 1; off < 256; off <<= 1) {
    int u = (t >= off) ? lrp[t - off] : 0;
    __syncthreads();
    lrp[t] += u;
    __syncthreads();
  }
  const int incl = lrp[t];
  if (t == 255) shtot = incl;
  const int ex = incl - sz;
  lex[t] = ex;
  lng[t] = ng0;
  __syncthreads();   // publish lex / lng / shtot
  const int btot = shtot;
  if (t < 32) cstage[btot + t] = NN;   // tail pads for k_agg prefetch over-read
  rps[node] = b * BCI2 + ex;           // written for ALL slots (invalid -> sz 0)
  rpc[node] = ng0 | (ng1 << 16);
  if (valid) {
    isd[node] = rsqrtf((float)(deg0 + 1));
    isd[NN + node] = rsqrtf((float)(deg1 + 1));
    cstage[ex + deg0] = node;                                // r0 self
    for (int p = deg0 + 1; p < (ng0 << 3); ++p) cstage[ex + p] = NN;
    const int ex1 = ex + (ng0 << 3);
    cstage[ex1 + deg1] = (NN + 1) + node;                    // r1 self
    for (int p = deg1 + 1; p < (ng1 << 3); ++p) cstage[ex1 + p] = NN;
  }
  // scatter (disjoint positions vs pads/self; lex/lng published above)
  for (int s = t; s < cnt0; s += 256) {
    uint pr = bd0[s];
    int j = (int)(pr & 255u);
    int p = atomicAdd(&lcurA[j], 1);
    cstage[lex[j] + p] = (int)(pr >> 8);
  }
  for (int s = t; s < cnt1; s += 256) {
    uint pr = bd1[s];
    int j = (int)(pr & 255u);
    int p = atomicAdd(&lcurB[j], 1);
    cstage[lex[j] + (lng[j] << 3) + p] = (int)(pr >> 8) + (NN + 1);
  }
  __syncthreads();
  const int on = btot + 32;
  int* co = ci + (size_t)b * BCI2;
  for (int s = t; s < on; s += 256) co[s] = cstage[s];
}

// ---------------- MFMA GEMM: xw'[r][m][:] = (X[m][:] @ W[r]) * isd[r][m], fp8 out ----------------
#define AL_S 72    // 64+8 bf16 row stride
#define WT_S 136   // 128+8 bf16 row stride
template <int IN_BF16>
__global__ __launch_bounds__(256) void k_gemm(const void* __restrict__ Xv,
                                              const ushort* __restrict__ WTg,
                                              const float* __restrict__ isd,
                                              uint* __restrict__ Y) {
  __shared__ ushort WTl[128 * WT_S];
  __shared__ ushort Al[128 * AL_S];
  const int r = blockIdx.y;
  const int m0b = blockIdx.x * 128;
  const int t = threadIdx.x;
  const int w = t >> 6, L = t & 63, q = L >> 4, ln = L & 15;
  uint* Yr = Y + (size_t)r * (NN + 1) * 32;   // fp8 row = 32 uints, +1 zero row
  const ushort* WTr = WTg + (size_t)r * 16384;

#pragma unroll
  for (int i = 0; i < 8; ++i) {
    int g = t + i * 256;
    int n = g >> 4, k0 = (g & 15) * 8;
    *(uint4*)(&WTl[n * WT_S + k0]) = *(const uint4*)(WTr + n * 128 + k0);
  }

  f32x4 acc[2][8];
#pragma unroll
  for (int mt = 0; mt < 2; ++mt)
#pragma unroll
    for (int nt = 0; nt < 8; ++nt) {
      acc[mt][nt][0] = 0.f; acc[mt][nt][1] = 0.f;
      acc[mt][nt][2] = 0.f; acc[mt][nt][3] = 0.f;
    }

  for (int hh = 0; hh < 2; ++hh) {
    __syncthreads();
    {
      int row = t >> 1, ch = t & 1;
      int gm = m0b + row;
      ushort* dst = &Al[row * AL_S + ch * 32];
      if (gm < NN) {
        if (IN_BF16) {
          const uint4* xp = (const uint4*)((const ushort*)Xv + (size_t)gm * 128 + hh * 64 + ch * 32);
#pragma unroll
          for (int j = 0; j < 4; ++j) ((uint4*)dst)[j] = xp[j];
        } else {
          const float4* xp = (const float4*)((const float*)Xv + (size_t)gm * 128 + hh * 64 + ch * 32);
          ushort tmp[32];
#pragma unroll
          for (int j = 0; j < 8; ++j) {
            float4 v = xp[j];
            tmp[j * 4 + 0] = f2b(v.x); tmp[j * 4 + 1] = f2b(v.y);
            tmp[j * 4 + 2] = f2b(v.z); tmp[j * 4 + 3] = f2b(v.w);
          }
#pragma unroll
          for (int j = 0; j < 4; ++j) ((uint4*)dst)[j] = ((uint4*)tmp)[j];
        }
      } else {
        uint4 z = make_uint4(0, 0, 0, 0);
#pragma unroll
        for (int j = 0; j < 4; ++j) ((uint4*)dst)[j] = z;
      }
    }
    __syncthreads();
#pragma unroll
    for (int kk = 0; kk < 2; ++kk) {
      bf16x8 b0 = *(const bf16x8*)(&Al[(w * 32 + ln) * AL_S + kk * 32 + q * 8]);
      bf16x8 b1 = *(const bf16x8*)(&Al[(w * 32 + 16 + ln) * AL_S + kk * 32 + q * 8]);
#pragma unroll
      for (int nt = 0; nt < 8; ++nt) {
        bf16x8 a = *(const bf16x8*)(&WTl[(nt * 16 + ln) * WT_S + hh * 64 + kk * 32 + q * 8]);
        acc[0][nt] = __builtin_amdgcn_mfma_f32_16x16x32_bf16(a, b0, acc[0][nt], 0, 0, 0);
        acc[1][nt] = __builtin_amdgcn_mfma_f32_16x16x32_bf16(a, b1, acc[1][nt], 0, 0, 0);
      }
    }
  }
  // epilogue: lane holds D for m = m0b + w*32 + mt*16 + ln, n = nt*16 + q*4 + reg
  // m == NN is the zero row used by k_agg's pad slots (acc==0 there since Al was zeroed).
#pragma unroll
  for (int mt = 0; mt < 2; ++mt) {
    int m = m0b + w * 32 + mt * 16 + ln;
    if (m <= NN) {
      float sc = (m < NN) ? isd[r * NN + m] : 0.f;
      uint* yp = Yr + (size_t)m * 32;
#pragma unroll
      for (int nt = 0; nt < 8; ++nt) {
        f32x4 v = acc[mt][nt];
        uint u = __builtin_amdgcn_cvt_pk_fp8_f32(v[0] * sc, v[1] * sc, 0u, false);
        u = __builtin_amdgcn_cvt_pk_fp8_f32(v[2] * sc, v[3] * sc, u, true);
        yp[nt * 4 + q] = u;
      }
    }
  }
}

// ---------------- aggregation: 1 wave per 4 CONSECUTIVE nodes, one streaming pipeline ----------------
// lane = g*8 + c: g = edge slot (0..7), c = channel-quad (16 fp8 ch = 1 uint4).
// Merged segments are contiguous, so the depth-2-data / depth-3-index pipeline runs
// across relation and node boundaries with ONE fill per wave. No bounds checks in the
// steady loop (pads hit the zero row). Per-relation di applied at sub-segment ends.
#define AGG_STEP()                                                           \
  {                                                                          \
    int s3 = ce0[ip]; ip += 8;                                               \
    uint4 u2 = *(const uint4*)(xw + ((size_t)((uint)s2 << 7) + cb));         \
    f32x2 v;                                                                 \
    v = __builtin_amdgcn_cvt_pk_f32_fp8(u0.x, false); acc[0] += v;           \
    v = __builtin_amdgcn_cvt_pk_f32_fp8(u0.x, true);  acc[1] += v;           \
    v = __builtin_amdgcn_cvt_pk_f32_fp8(u0.y, false); acc[2] += v;           \
    v = __builtin_amdgcn_cvt_pk_f32_fp8(u0.y, true);  acc[3] += v;           \
    v = __builtin_amdgcn_cvt_pk_f32_fp8(u0.z, false); acc[4] += v;           \
    v = __builtin_amdgcn_cvt_pk_f32_fp8(u0.z, true);  acc[5] += v;           \
    v = __builtin_amdgcn_cvt_pk_f32_fp8(u0.w, false); acc[6] += v;           \
    v = __builtin_amdgcn_cvt_pk_f32_fp8(u0.w, true);  acc[7] += v;           \
    u0 = u1; u1 = u2; s2 = s3;                                               \
  }

__global__ __launch_bounds__(256) void k_agg(const char* __restrict__ xw,
                                             const int* __restrict__ rps,
                                             const int* __restrict__ rpc,
                                             const int* __restrict__ ci,
                                             const float* __restrict__ isd,
                                             const float* __restrict__ bias,
                                             uint* __restrict__ hout, int relu_flag) {
  const int w = threadIdx.x >> 6;
  const int lane = threadIdx.x & 63;
  const int g = lane >> 3, c = lane & 7;
  const int wid = blockIdx.x * 4 + w;                 // 0..12543
  const int n0 = (wid >> 6) * 256 + (wid & 63) * 4;   // 4 consecutive nodes in one bucket
  const size_t cb = (size_t)c * 16;

  const int m0 = rpc[n0], m1 = rpc[n0 + 1], m2 = rpc[n0 + 2], m3 = rpc[n0 + 3];
  const int* ce0 = ci + rps[n0];

  // pipeline fill: 3 indices, 2 data loads in flight
  int ip = g;
  int s0 = ce0[ip]; ip += 8;
  int s1 = ce0[ip]; ip += 8;
  int s2 = ce0[ip]; ip += 8;
  uint4 u0 = *(const uint4*)(xw + ((size_t)((uint)s0 << 7) + cb));
  uint4 u1 = *(const uint4*)(xw + ((size_t)((uint)s1 << 7) + cb));

#pragma unroll
  for (int k = 0; k < 4; ++k) {
    const int node = n0 + k;
    const int meta_k = (k == 0) ? m0 : (k == 1) ? m1 : (k == 2) ? m2 : m3;
    const int ng0 = meta_k & 0xffff;
    const int ng1 = (meta_k >> 16) & 0xffff;
    const float di0 = isd[node];
    const float di1 = isd[NN + node];

    f32x2 acc[8];
#pragma unroll
    for (int j = 0; j < 8; ++j) { acc[j][0] = 0.f; acc[j][1] = 0.f; }
    for (int q = 0; q < ng0; ++q) AGG_STEP();
    f32x2 t8[8];
    {
      f32x2 d; d[0] = di0; d[1] = di0;
#pragma unroll
      for (int j = 0; j < 8; ++j) { t8[j] = acc[j] * d; acc[j][0] = 0.f; acc[j][1] = 0.f; }
    }
    for (int q = 0; q < ng1; ++q) AGG_STEP();
    {
      f32x2 d; d[0] = di1; d[1] = di1;
#pragma unroll
      for (int j = 0; j < 8; ++j) t8[j] += acc[j] * d;
    }

    // reduce over 8 edge slots (lane bits 3,4,5)
#pragma unroll
    for (int mask = 8; mask <= 32; mask <<= 1) {
#pragma unroll
      for (int j = 0; j < 8; ++j) {
        f32x2 o;
        o[0] = __shfl_xor(t8[j][0], mask);
        o[1] = __shfl_xor(t8[j][1], mask);
        t8[j] += o;
      }
    }

    if (g == 0 && node < NN) {    // lanes 0..7 write channels [c*16, c*16+16)
      const float4* p0 = (const float4*)(bias + c * 16);
      const float4* p1 = (const float4*)(bias + DD + c * 16);
      float o[16];
#pragma unroll
      for (int j = 0; j < 4; ++j) {
        float4 a = p0[j], bq = p1[j];
        o[4 * j + 0] = t8[2 * j][0] + a.x + bq.x;
        o[4 * j + 1] = t8[2 * j][1] + a.y + bq.y;
        o[4 * j + 2] = t8[2 * j + 1][0] + a.z + bq.z;
        o[4 * j + 3] = t8[2 * j + 1][1] + a.w + bq.w;
      }
      if (relu_flag) {
#pragma unroll
        for (int j = 0; j < 16; ++j) o[j] = fmaxf(o[j], 0.f);
      }
      uint pk[8];
#pragma unroll
      for (int j = 0; j < 8; ++j)
        pk[j] = (uint)f2b(o[2 * j]) | ((uint)f2b(o[2 * j + 1]) << 16);
      uint4* dst = (uint4*)(hout + (size_t)node * 64) + c * 2;
      dst[0] = make_uint4(pk[0], pk[1], pk[2], pk[3]);
      dst[1] = make_uint4(pk[4], pk[5], pk[6], pk[7]);
    }
  }
}

// ---------------- pooling (batch ids sorted), packed bf16 input ----------------
#define PCHUNK 32
__global__ __launch_bounds__(64) void k_pool(const uint* __restrict__ h,
                                             const int* __restrict__ batch,
                                             float* __restrict__ sums,
                                             int* __restrict__ counts) {
  int lane = threadIdx.x;
  int n0 = blockIdx.x * PCHUNK;
  int n1 = n0 + PCHUNK;
  if (n1 > NN) n1 = NN;
  if (n0 >= NN) return;
  float aLo = 0.f, aHi = 0.f;
  int cnt = 0;
  int g = batch[n0];
  uint u = h[(size_t)n0 * 64 + lane];
  for (int n = n0; n < n1; ++n) {
    uint unext = 0;
    int gnext = g;
    if (n + 1 < n1) {
      unext = h[(size_t)(n + 1) * 64 + lane];
      gnext = batch[n + 1];
    }
    aLo += blo(u);
    aHi += bhi(u);
    cnt++;
    if (n + 1 < n1 && gnext != g) {
      atomicAdd(&sums[g * DD + lane * 2], aLo);
      atomicAdd(&sums[g * DD + lane * 2 + 1], aHi);
      if (lane == 0) atomicAdd(&counts[g], cnt);
      aLo = 0.f; aHi = 0.f; cnt = 0;
      g = gnext;
    }
    u = unext;
  }
  atomicAdd(&sums[g * DD + lane * 2], aLo);
  atomicAdd(&sums[g * DD + lane * 2 + 1], aHi);
  if (lane == 0) atomicAdd(&counts[g], cnt);
}

__global__ __launch_bounds__(512) void k_final(const float* __restrict__ sums,
                                               const int* __restrict__ counts,
                                               const float* __restrict__ lin_w,
                                               const float* __restrict__ lin_b,
                                               float* __restrict__ out) {
  int t = threadIdx.x;  // 512 = 64 graphs x 8 classes
  int g = t >> 3, co = t & 7;
  float cnt = (float)counts[g];
  if (cnt < 1.f) cnt = 1.f;
  float inv = 1.f / cnt;
  float v = lin_b[co];
  for (int d = 0; d < DD; ++d) v += (sums[g * DD + d] * inv) * lin_w[d * CCLS + co];
  out[t] = v;
}

extern "C" void kernel_launch(void* const* d_in, const int* in_sizes, int n_in,
                              void* d_out, int out_size, void* d_ws, size_t ws_size,
                              hipStream_t stream) {
  (void)in_sizes; (void)n_in; (void)out_size; (void)ws_size;
  const float* x     = (const float*)d_in[0];
  const float* W     = (const float*)d_in[1];
  const float* b     = (const float*)d_in[2];
  const float* lin_w = (const float*)d_in[3];
  const float* lin_b = (const float*)d_in[4];
  const int*   EI    = (const int*)d_in[5];
  const int*   batch = (const int*)d_in[6];
  float* out = (float*)d_out;

  char* ws = (char*)d_ws;
  uint*   h1    = (uint*)(ws + OFF_H1);       // bf16 packed
  ushort* WbfT  = (ushort*)(ws + OFF_WBT);
  float*  isd   = (float*)(ws + OFF_ISD);
  int*    rps   = (int*)(ws + OFF_RP);
  int*    rpc   = rps + NBUK * 256;
  int*    ci    = (int*)(ws + OFF_CI);
  uint*   bdata = (uint*)(ws + OFF_BD);
  uint*   xw    = (uint*)(ws + OFF_XW);       // fp8 table (isd-prescaled), aliases bdata
  char*   zb    = ws + OFF_ZERO;
  int*    gcur  = (int*)(zb + ZO_GCUR);
  float*  sums  = (float*)(zb + ZO_SUM);
  int*    counts= (int*)(zb + ZO_CNT);

  (void)hipMemsetAsync(zb, 0, ZERO_BYTES, stream);

  k_wprep<<<256, 256, 0, stream>>>(W, WbfT);
  k_part<<<dim3((EE + 4095) / 4096, RR), 256, 0, stream>>>(EI, gcur, bdata);
  k_csr<<<NBUK, 256, 0, stream>>>(bdata, gcur, isd, rps, rpc, ci);

  for (int l = 0; l < LL; ++l) {
    const ushort* WTl_g = WbfT + (size_t)l * RR * DD * DD;
    if (l == 0)
      k_gemm<0><<<dim3((NN + 127) / 128, RR), 256, 0, stream>>>((const void*)x, WTl_g, isd, xw);
    else
      k_gemm<1><<<dim3((NN + 127) / 128, RR), 256, 0, stream>>>((const void*)h1, WTl_g, isd, xw);
    k_agg<<<(NBUK * 64) / 4, 256, 0, stream>>>((const char*)xw, rps, rpc, ci, isd,
                                               b + (size_t)l * RR * DD, h1,
                                               (l < LL - 1) ? 1 : 0);
  }
  k_pool<<<(NN + PCHUNK - 1) / PCHUNK, 64, 0, stream>>>(h1, batch, sums, counts);
  k_final<<<1, GG * CCLS, 0, stream>>>(sums, counts, lin_w, lin_b, out);
}

// Round 4
// 272.741 us; speedup vs baseline: 1.0607x; 1.0562x over previous
//
#include <hip/hip_runtime.h>
#include <math.h>

#define NN 50000
#define EE 800000
#define RR 2
#define LL 2
#define DD 128
#define GG 64
#define CCLS 8
#define NBUK 196     // buckets of 256 dst nodes: bucket = dst >> 8
#define BCAP 6144    // max raw edges per bucket per relation (mean 4082, sigma 64)
#define BCI2 14080   // merged bucket CSR capacity (r0+r1 jointly padded to %8, +32 tail)
                     // worst: 2*(4082+6sig) + 256*2 self + 256*7 pad + 32 ~= 11.3k < 14080

typedef unsigned int uint;
typedef unsigned short ushort;
typedef short bf16x8 __attribute__((ext_vector_type(8)));
typedef float f32x4 __attribute__((ext_vector_type(4)));
typedef float f32x2 __attribute__((ext_vector_type(2)));

// ---------------- workspace layout (bytes) ----------------
#define OFF_H1    ((size_t)0)            // [N][64] uint packed bf16      12,800,000
#define OFF_WBT   ((size_t)12800000)     // [L][R][128][128] bf16            131,072
#define OFF_ISD   ((size_t)12931072)     // [2][N] f32                       400,000
#define OFF_RP    ((size_t)13331072)     // rps[50176] + rpc[50176] i32      401,408
#define OFF_CI    ((size_t)13732480)     // [196][BCI2] i32               11,038,720
#define OFF_ZERO  ((size_t)24771200)     // 34,624
#define OFF_BD    ((size_t)24805824)     // [2][196][BCAP] uint            9,633,792
#define OFF_XW    ((size_t)24805824)     // ALIAS of BD (bdata dead after k_csr):
                                         // [2][N+1][128] fp8             12,800,256
// zero region internal offsets (bytes)
#define ZO_GCUR 0        // [2][196] i32 bucket counters (1568 B, pad 1600)
#define ZO_SUM  1600     // [G][D] f32 (32768 B)
#define ZO_CNT  34368    // [G] i32 (256 B)
#define ZERO_BYTES 34624

static __device__ __forceinline__ ushort f2b(float f) {
  uint u = __float_as_uint(f);
  uint r = (u + 0x7fffu + ((u >> 16) & 1u)) >> 16;
  return (ushort)r;
}
static __device__ __forceinline__ float blo(uint u) { return __uint_as_float(u << 16); }
static __device__ __forceinline__ float bhi(uint u) { return __uint_as_float(u & 0xffff0000u); }

// ---------------- W prep: fp32 W[l][r][k][n] -> bf16 WbfT[l][r][n][k] ----------------
__global__ __launch_bounds__(256) void k_wprep(const float* __restrict__ W,
                                               ushort* __restrict__ WT) {
  int idx = blockIdx.x * 256 + threadIdx.x;  // 65536 total
  int lr = idx >> 14;
  int rem = idx & 16383;
  int n = rem >> 7, k = rem & 127;
  WT[lr * 16384 + n * 128 + k] = f2b(W[lr * 16384 + k * 128 + n]);
}

// ---------------- phase 1: partition edges into dst buckets (coalesced) ----------------
__global__ __launch_bounds__(256) void k_part(const int* __restrict__ EI,
                                              int* __restrict__ gcur,
                                              uint* __restrict__ bdata) {
  __shared__ int hist[256];   // bucket counts -> stage-exclusive offsets
  __shared__ int sbase[256];  // scan scratch
  __shared__ int gbase[256];  // global reservation base per bucket
  __shared__ int lcur[256];
  __shared__ uint stage[4096];
  __shared__ unsigned char bstage[4096];
  const int r = blockIdx.y;
  const int t = threadIdx.x;
  const int e0 = blockIdx.x * 4096;
  const int cnt = min(4096, EE - e0);
  hist[t] = 0;
  lcur[t] = 0;
  __syncthreads();

  int src[16], dst[16];
  bool val[4];
#pragma unroll
  for (int j = 0; j < 4; ++j) {
    int i4 = (j * 256 + t) * 4;
    val[j] = (i4 < cnt);
    if (val[j]) {
      int4 s4 = *(const int4*)(EI + (size_t)r * 2 * EE + e0 + i4);
      int4 d4 = *(const int4*)(EI + (size_t)r * 2 * EE + EE + e0 + i4);
      src[j * 4 + 0] = s4.x; src[j * 4 + 1] = s4.y; src[j * 4 + 2] = s4.z; src[j * 4 + 3] = s4.w;
      dst[j * 4 + 0] = d4.x; dst[j * 4 + 1] = d4.y; dst[j * 4 + 2] = d4.z; dst[j * 4 + 3] = d4.w;
#pragma unroll
      for (int i = 0; i < 4; ++i) atomicAdd(&hist[dst[j * 4 + i] >> 8], 1);
    }
  }
  __syncthreads();
  int hv = hist[t];
  if (t < NBUK && hv > 0)
    gbase[t] = atomicAdd(&gcur[r * NBUK + t], hv);
  else
    gbase[t] = 0;
  sbase[t] = hv;
  __syncthreads();
  for (int off = 1; off < 256; off <<= 1) {
    int u = (t >= off) ? sbase[t - off] : 0;
    __syncthreads();
    sbase[t] += u;
    __syncthreads();
  }
  int incl = sbase[t];
  hist[t] = incl - hv;  // exclusive stage offset
  __syncthreads();
#pragma unroll
  for (int j = 0; j < 4; ++j) {
    if (val[j]) {
#pragma unroll
      for (int i = 0; i < 4; ++i) {
        int d = dst[j * 4 + i];
        int b = d >> 8;
        int p = atomicAdd(&lcur[b], 1);
        int pos = hist[b] + p;
        stage[pos] = ((uint)src[j * 4 + i] << 8) | (uint)(d & 255);
        bstage[pos] = (unsigned char)b;
      }
    }
  }
  __syncthreads();
  for (int s = t; s < cnt; s += 256) {
    int b = (int)bstage[s];
    bdata[(size_t)(r * NBUK + b) * BCAP + gbase[b] + (s - hist[b])] = stage[s];
  }
}

// ---------------- phase 2: merged per-node CSR, JOINTLY padded to %8 ----------------
// Per node: [r0 edges..., self(node), r1 edges+(NN+1)..., self(NN+1+node), pads(NN)]
// padded to a multiple of 8 across BOTH relations. end0 = deg0+1 marks the r0/r1
// boundary slot; k_agg selects di0/di1 per slot. Row NN of the fp8 table is zero.
__global__ __launch_bounds__(256) void k_csr(const uint* __restrict__ bdata,
                                             const int* __restrict__ gcur,
                                             float* __restrict__ isd,
                                             int* __restrict__ rps,
                                             int* __restrict__ rpc,
                                             int* __restrict__ ci) {
  __shared__ int lcnt0[256], lcnt1[256], lrp[256], lex[256], lend0[256];
  __shared__ int lcurA[256], lcurB[256];
  __shared__ int cstage[BCI2];   // 56,320 B (+7 KB arrays = 63.3 KB, under 64 KB)
  __shared__ int shtot;
  const int b = blockIdx.x;
  const int t = threadIdx.x;
  const int cnt0 = gcur[b];
  const int cnt1 = gcur[NBUK + b];
  const uint* bd0 = bdata + (size_t)b * BCAP;
  const uint* bd1 = bdata + (size_t)(NBUK + b) * BCAP;
  lcnt0[t] = 0; lcnt1[t] = 0; lcurA[t] = 0; lcurB[t] = 0;
  __syncthreads();
  for (int s = t; s < cnt0; s += 256) atomicAdd(&lcnt0[bd0[s] & 255u], 1);
  for (int s = t; s < cnt1; s += 256) atomicAdd(&lcnt1[bd1[s] & 255u], 1);
  __syncthreads();
  const int deg0 = lcnt0[t];
  const int deg1 = lcnt1[t];
  const int node = b * 256 + t;
  const int valid = (node < NN) ? 1 : 0;
  const int nreal = deg0 + deg1 + 2;               // + both selfs
  const int ng = valid ? ((nreal + 7) >> 3) : 0;   // joint pad to %8
  const int sz = ng << 3;
  const int end0 = deg0 + 1;
  lrp[t] = sz;
  __syncthreads();
  for (int off = 1; off < 256; off <<= 1) {
    int u = (t >= off) ? lrp[t - off] : 0;
    __syncthreads();
    lrp[t] += u;
    __syncthreads();
  }
  const int incl = lrp[t];
  if (t == 255) shtot = incl;
  const int ex = incl - sz;
  lex[t] = ex;
  lend0[t] = end0;
  __syncthreads();   // publish lex / lend0 / shtot
  const int btot = shtot;
  if (t < 32) cstage[btot + t] = NN;   // tail pads for k_agg index over-read
  rps[node] = b * BCI2 + ex;           // written for ALL slots
  rpc[node] = valid ? (ng | (end0 << 16)) : 0;
  if (valid) {
    isd[node] = rsqrtf((float)(deg0 + 1));
    isd[NN + node] = rsqrtf((float)(deg1 + 1));
    cstage[ex + deg0] = node;                         // r0 self at slot deg0
    cstage[ex + end0 + deg1] = (NN + 1) + node;       // r1 self
    for (int p = end0 + deg1 + 1; p < sz; ++p) cstage[ex + p] = NN;  // zero-row pads
  }
  // scatter (disjoint positions vs pads/selfs; lex/lend0 published above)
  for (int s = t; s < cnt0; s += 256) {
    uint pr = bd0[s];
    int j = (int)(pr & 255u);
    int p = atomicAdd(&lcurA[j], 1);
    cstage[lex[j] + p] = (int)(pr >> 8);
  }
  for (int s = t; s < cnt1; s += 256) {
    uint pr = bd1[s];
    int j = (int)(pr & 255u);
    int p = atomicAdd(&lcurB[j], 1);
    cstage[lex[j] + lend0[j] + p] = (int)(pr >> 8) + (NN + 1);
  }
  __syncthreads();
  const int on = btot + 32;
  int* co = ci + (size_t)b * BCI2;
  for (int s = t; s < on; s += 256) co[s] = cstage[s];
}

// ---------------- MFMA GEMM: xw'[r][m][:] = (X[m][:] @ W[r]) * isd[r][m], fp8 out ----------------
#define AL_S 72    // 64+8 bf16 row stride
#define WT_S 136   // 128+8 bf16 row stride
template <int IN_BF16>
__global__ __launch_bounds__(256) void k_gemm(const void* __restrict__ Xv,
                                              const ushort* __restrict__ WTg,
                                              const float* __restrict__ isd,
                                              uint* __restrict__ Y) {
  __shared__ ushort WTl[128 * WT_S];
  __shared__ ushort Al[128 * AL_S];
  const int r = blockIdx.y;
  const int m0b = blockIdx.x * 128;
  const int t = threadIdx.x;
  const int w = t >> 6, L = t & 63, q = L >> 4, ln = L & 15;
  uint* Yr = Y + (size_t)r * (NN + 1) * 32;   // fp8 row = 32 uints, +1 zero row
  const ushort* WTr = WTg + (size_t)r * 16384;

#pragma unroll
  for (int i = 0; i < 8; ++i) {
    int g = t + i * 256;
    int n = g >> 4, k0 = (g & 15) * 8;
    *(uint4*)(&WTl[n * WT_S + k0]) = *(const uint4*)(WTr + n * 128 + k0);
  }

  f32x4 acc[2][8];
#pragma unroll
  for (int mt = 0; mt < 2; ++mt)
#pragma unroll
    for (int nt = 0; nt < 8; ++nt) {
      acc[mt][nt][0] = 0.f; acc[mt][nt][1] = 0.f;
      acc[mt][nt][2] = 0.f; acc[mt][nt][3] = 0.f;
    }

  for (int hh = 0; hh < 2; ++hh) {
    __syncthreads();
    {
      int row = t >> 1, ch = t & 1;
      int gm = m0b + row;
      ushort* dst = &Al[row * AL_S + ch * 32];
      if (gm < NN) {
        if (IN_BF16) {
          const uint4* xp = (const uint4*)((const ushort*)Xv + (size_t)gm * 128 + hh * 64 + ch * 32);
#pragma unroll
          for (int j = 0; j < 4; ++j) ((uint4*)dst)[j] = xp[j];
        } else {
          const float4* xp = (const float4*)((const float*)Xv + (size_t)gm * 128 + hh * 64 + ch * 32);
          ushort tmp[32];
#pragma unroll
          for (int j = 0; j < 8; ++j) {
            float4 v = xp[j];
            tmp[j * 4 + 0] = f2b(v.x); tmp[j * 4 + 1] = f2b(v.y);
            tmp[j * 4 + 2] = f2b(v.z); tmp[j * 4 + 3] = f2b(v.w);
          }
#pragma unroll
          for (int j = 0; j < 4; ++j) ((uint4*)dst)[j] = ((uint4*)tmp)[j];
        }
      } else {
        uint4 z = make_uint4(0, 0, 0, 0);
#pragma unroll
        for (int j = 0; j < 4; ++j) ((uint4*)dst)[j] = z;
      }
    }
    __syncthreads();
#pragma unroll
    for (int kk = 0; kk < 2; ++kk) {
      bf16x8 b0 = *(const bf16x8*)(&Al[(w * 32 + ln) * AL_S + kk * 32 + q * 8]);
      bf16x8 b1 = *(const bf16x8*)(&Al[(w * 32 + 16 + ln) * AL_S + kk * 32 + q * 8]);
#pragma unroll
      for (int nt = 0; nt < 8; ++nt) {
        bf16x8 a = *(const bf16x8*)(&WTl[(nt * 16 + ln) * WT_S + hh * 64 + kk * 32 + q * 8]);
        acc[0][nt] = __builtin_amdgcn_mfma_f32_16x16x32_bf16(a, b0, acc[0][nt], 0, 0, 0);
        acc[1][nt] = __builtin_amdgcn_mfma_f32_16x16x32_bf16(a, b1, acc[1][nt], 0, 0, 0);
      }
    }
  }
  // epilogue: lane holds D for m = m0b + w*32 + mt*16 + ln, n = nt*16 + q*4 + reg
  // m == NN is the zero row used by k_agg's pad slots (acc==0 there since Al was zeroed).
#pragma unroll
  for (int mt = 0; mt < 2; ++mt) {
    int m = m0b + w * 32 + mt * 16 + ln;
    if (m <= NN) {
      float sc = (m < NN) ? isd[r * NN + m] : 0.f;
      uint* yp = Yr + (size_t)m * 32;
#pragma unroll
      for (int nt = 0; nt < 8; ++nt) {
        f32x4 v = acc[mt][nt];
        uint u = __builtin_amdgcn_cvt_pk_fp8_f32(v[0] * sc, v[1] * sc, 0u, false);
        u = __builtin_amdgcn_cvt_pk_fp8_f32(v[2] * sc, v[3] * sc, u, true);
        yp[nt * 4 + q] = u;
      }
    }
  }
}

// ---------------- aggregation: 1 wave/node, depth-3 gather pipeline ----------------
// lane = g*8 + c: g = edge slot (0..7), c = channel-quad (16 fp8 ch = 1 uint4).
// Merged per-node segment (r0 then r1, jointly padded to %8): ONE pipeline fill per
// node, per-slot di0/di1 select via pk_fma. Prefetch indices clamped to the zero row
// so speculative gathers past the segment coalesce onto 2 hot cache lines.
__global__ __launch_bounds__(256, 6) void k_agg(const char* __restrict__ xw,
                                                const int* __restrict__ rps,
                                                const int* __restrict__ rpc,
                                                const int* __restrict__ ci,
                                                const float* __restrict__ isd,
                                                const float* __restrict__ bias,
                                                uint* __restrict__ hout, int relu_flag) {
  const int w = threadIdx.x >> 6;
  const int lane = threadIdx.x & 63;
  const int g = lane >> 3, c = lane & 7;
  const int node = blockIdx.x * 4 + w;     // 0..50175 (contiguous within buckets)
  const size_t cb = (size_t)c * 16;

  const int meta = rpc[node];
  const int ng = meta & 0xffff;
  const int end0 = (meta >> 16) & 0xffff;
  const int lim = ng << 3;
  const int* ce = ci + rps[node];
  const float di0 = isd[node < NN ? node : 0];
  const float di1 = isd[NN + (node < NN ? node : 0)];

  // pipeline fill: 3 data gathers + 4th index in flight, indices clamped to zero row
  int ip = g;
  int s0 = ce[ip]; s0 = (ip < lim) ? s0 : NN; ip += 8;
  uint4 d0 = *(const uint4*)(xw + (((size_t)(uint)s0 << 7) + cb));
  int s1 = ce[ip]; s1 = (ip < lim) ? s1 : NN; ip += 8;
  uint4 d1 = *(const uint4*)(xw + (((size_t)(uint)s1 << 7) + cb));
  int s2 = ce[ip]; s2 = (ip < lim) ? s2 : NN; ip += 8;
  uint4 d2 = *(const uint4*)(xw + (((size_t)(uint)s2 << 7) + cb));

  f32x2 acc[8];
#pragma unroll
  for (int j = 0; j < 8; ++j) { acc[j][0] = 0.f; acc[j][1] = 0.f; }

  int slotc = g;
  for (int q = 0; q < ng; ++q) {
    int s3 = ce[ip]; s3 = (ip < lim) ? s3 : NN; ip += 8;
    uint4 d3 = *(const uint4*)(xw + (((size_t)(uint)s3 << 7) + cb));  // keep 3 in flight
    const float sc = (slotc < end0) ? di0 : di1;
    slotc += 8;
    f32x2 sc2; sc2[0] = sc; sc2[1] = sc;
    f32x2 v;
    v = __builtin_amdgcn_cvt_pk_f32_fp8(d0.x, false); acc[0] += v * sc2;
    v = __builtin_amdgcn_cvt_pk_f32_fp8(d0.x, true);  acc[1] += v * sc2;
    v = __builtin_amdgcn_cvt_pk_f32_fp8(d0.y, false); acc[2] += v * sc2;
    v = __builtin_amdgcn_cvt_pk_f32_fp8(d0.y, true);  acc[3] += v * sc2;
    v = __builtin_amdgcn_cvt_pk_f32_fp8(d0.z, false); acc[4] += v * sc2;
    v = __builtin_amdgcn_cvt_pk_f32_fp8(d0.z, true);  acc[5] += v * sc2;
    v = __builtin_amdgcn_cvt_pk_f32_fp8(d0.w, false); acc[6] += v * sc2;
    v = __builtin_amdgcn_cvt_pk_f32_fp8(d0.w, true);  acc[7] += v * sc2;
    d0 = d1; d1 = d2; d2 = d3;
  }

  // reduce over 8 edge slots (lane bits 3,4,5)
#pragma unroll
  for (int mask = 8; mask <= 32; mask <<= 1) {
#pragma unroll
    for (int j = 0; j < 8; ++j) {
      f32x2 o;
      o[0] = __shfl_xor(acc[j][0], mask);
      o[1] = __shfl_xor(acc[j][1], mask);
      acc[j] += o;
    }
  }

  if (g == 0 && node < NN) {    // lanes 0..7 write channels [c*16, c*16+16)
    const float4* p0 = (const float4*)(bias + c * 16);
    const float4* p1 = (const float4*)(bias + DD + c * 16);
    float o[16];
#pragma unroll
    for (int j = 0; j < 4; ++j) {
      float4 a = p0[j], bq = p1[j];
      o[4 * j + 0] = acc[2 * j][0] + a.x + bq.x;
      o[4 * j + 1] = acc[2 * j][1] + a.y + bq.y;
      o[4 * j + 2] = acc[2 * j + 1][0] + a.z + bq.z;
      o[4 * j + 3] = acc[2 * j + 1][1] + a.w + bq.w;
    }
    if (relu_flag) {
#pragma unroll
      for (int j = 0; j < 16; ++j) o[j] = fmaxf(o[j], 0.f);
    }
    uint pk[8];
#pragma unroll
    for (int j = 0; j < 8; ++j)
      pk[j] = (uint)f2b(o[2 * j]) | ((uint)f2b(o[2 * j + 1]) << 16);
    uint4* dst = (uint4*)(hout + (size_t)node * 64) + c * 2;
    dst[0] = make_uint4(pk[0], pk[1], pk[2], pk[3]);
    dst[1] = make_uint4(pk[4], pk[5], pk[6], pk[7]);
  }
}

// ---------------- pooling (batch ids sorted), packed bf16 input ----------------
#define PCHUNK 32
__global__ __launch_bounds__(64) void k_pool(const uint* __restrict__ h,
                                             const int* __restrict__ batch,
                                             float* __restrict__ sums,
                                             int* __restrict__ counts) {
  int lane = threadIdx.x;
  int n0 = blockIdx.x * PCHUNK;
  int n1 = n0 + PCHUNK;
  if (n1 > NN) n1 = NN;
  if (n0 >= NN) return;
  float aLo = 0.f, aHi = 0.f;
  int cnt = 0;
  int g = batch[n0];
  uint u = h[(size_t)n0 * 64 + lane];
  for (int n = n0; n < n1; ++n) {
    uint unext = 0;
    int gnext = g;
    if (n + 1 < n1) {
      unext = h[(size_t)(n + 1) * 64 + lane];
      gnext = batch[n + 1];
    }
    aLo += blo(u);
    aHi += bhi(u);
    cnt++;
    if (n + 1 < n1 && gnext != g) {
      atomicAdd(&sums[g * DD + lane * 2], aLo);
      atomicAdd(&sums[g * DD + lane * 2 + 1], aHi);
      if (lane == 0) atomicAdd(&counts[g], cnt);
      aLo = 0.f; aHi = 0.f; cnt = 0;
      g = gnext;
    }
    u = unext;
  }
  atomicAdd(&sums[g * DD + lane * 2], aLo);
  atomicAdd(&sums[g * DD + lane * 2 + 1], aHi);
  if (lane == 0) atomicAdd(&counts[g], cnt);
}

__global__ __launch_bounds__(512) void k_final(const float* __restrict__ sums,
                                               const int* __restrict__ counts,
                                               const float* __restrict__ lin_w,
                                               const float* __restrict__ lin_b,
                                               float* __restrict__ out) {
  int t = threadIdx.x;  // 512 = 64 graphs x 8 classes
  int g = t >> 3, co = t & 7;
  float cnt = (float)counts[g];
  if (cnt < 1.f) cnt = 1.f;
  float inv = 1.f / cnt;
  float v = lin_b[co];
  for (int d = 0; d < DD; ++d) v += (sums[g * DD + d] * inv) * lin_w[d * CCLS + co];
  out[t] = v;
}

extern "C" void kernel_launch(void* const* d_in, const int* in_sizes, int n_in,
                              void* d_out, int out_size, void* d_ws, size_t ws_size,
                              hipStream_t stream) {
  (void)in_sizes; (void)n_in; (void)out_size; (void)ws_size;
  const float* x     = (const float*)d_in[0];
  const float* W     = (const float*)d_in[1];
  const float* b     = (const float*)d_in[2];
  const float* lin_w = (const float*)d_in[3];
  const float* lin_b = (const float*)d_in[4];
  const int*   EI    = (const int*)d_in[5];
  const int*   batch = (const int*)d_in[6];
  float* out = (float*)d_out;

  char* ws = (char*)d_ws;
  uint*   h1    = (uint*)(ws + OFF_H1);       // bf16 packed
  ushort* WbfT  = (ushort*)(ws + OFF_WBT);
  float*  isd   = (float*)(ws + OFF_ISD);
  int*    rps   = (int*)(ws + OFF_RP);
  int*    rpc   = rps + NBUK * 256;
  int*    ci    = (int*)(ws + OFF_CI);
  uint*   bdata = (uint*)(ws + OFF_BD);
  uint*   xw    = (uint*)(ws + OFF_XW);       // fp8 table (isd-prescaled), aliases bdata
  char*   zb    = ws + OFF_ZERO;
  int*    gcur  = (int*)(zb + ZO_GCUR);
  float*  sums  = (float*)(zb + ZO_SUM);
  int*    counts= (int*)(zb + ZO_CNT);

  (void)hipMemsetAsync(zb, 0, ZERO_BYTES, stream);

  k_wprep<<<256, 256, 0, stream>>>(W, WbfT);
  k_part<<<dim3((EE + 4095) / 4096, RR), 256, 0, stream>>>(EI, gcur, bdata);
  k_csr<<<NBUK, 256, 0, stream>>>(bdata, gcur, isd, rps, rpc, ci);

  for (int l = 0; l < LL; ++l) {
    const ushort* WTl_g = WbfT + (size_t)l * RR * DD * DD;
    if (l == 0)
      k_gemm<0><<<dim3((NN + 127) / 128, RR), 256, 0, stream>>>((const void*)x, WTl_g, isd, xw);
    else
      k_gemm<1><<<dim3((NN + 127) / 128, RR), 256, 0, stream>>>((const void*)h1, WTl_g, isd, xw);
    k_agg<<<(NBUK * 256) / 4, 256, 0, stream>>>((const char*)xw, rps, rpc, ci, isd,
                                                b + (size_t)l * RR * DD, h1,
                                                (l < LL - 1) ? 1 : 0);
  }
  k_pool<<<(NN + PCHUNK - 1) / PCHUNK, 64, 0, stream>>>(h1, batch, sums, counts);
  k_final<<<1, GG * CCLS, 0, stream>>>(sums, counts, lin_w, lin_b, out);
}